// Round 4
// baseline (8803.036 us; speedup 1.0000x reference)
//
#include <hip/hip_runtime.h>
#include <math.h>

typedef unsigned short u16;
typedef unsigned int u32;
typedef __bf16 bfx8 __attribute__((ext_vector_type(8)));
typedef float fx4 __attribute__((ext_vector_type(4)));

// ---------------- numeric helpers ----------------
__device__ __forceinline__ float b2f(u16 v) { return __uint_as_float(((u32)v) << 16); }
__device__ __forceinline__ u16 f2b(float f) {  // round-to-nearest-even
    u32 u = __float_as_uint(f);
    u32 lsb = (u >> 16) & 1u;
    u += 0x7fffu + lsb;
    return (u16)(u >> 16);
}
__device__ __forceinline__ float4 unpack4(u32 a, u32 b) {
    float4 r;
    r.x = __uint_as_float(a << 16);
    r.y = __uint_as_float(a & 0xffff0000u);
    r.z = __uint_as_float(b << 16);
    r.w = __uint_as_float(b & 0xffff0000u);
    return r;
}
__device__ __forceinline__ float sigmoid_(float x) { return 1.f / (1.f + __expf(-x)); }
__device__ __forceinline__ float gelu_(float x) { return 0.5f * x * (1.f + erff(x * 0.7071067811865475f)); }

// dtype-adaptive scalar load/store: f==1 -> buffer is float32, else bf16
__device__ __forceinline__ float ldx(const void* p, long i, int f) {
    return f ? ((const float*)p)[i] : b2f(((const u16*)p)[i]);
}
__device__ __forceinline__ void stx(void* p, long i, float v, int f) {
    if (f) ((float*)p)[i] = v;
    else ((u16*)p)[i] = f2b(v);
}
// stage 8 consecutive elements (idx must be 8-aligned rel. to 16B) into LDS as bf16
__device__ __forceinline__ void stage8(u16* dst, const void* src, long idx, int f, bool ok) {
    uint4 r;
    if (!ok) {
        r = make_uint4(0u, 0u, 0u, 0u);
    } else if (f) {
        const float* p = (const float*)src + idx;
        float4 a = *(const float4*)p;
        float4 b = *(const float4*)(p + 4);
        r = make_uint4((u32)f2b(a.x) | ((u32)f2b(a.y) << 16),
                       (u32)f2b(a.z) | ((u32)f2b(a.w) << 16),
                       (u32)f2b(b.x) | ((u32)f2b(b.y) << 16),
                       (u32)f2b(b.z) | ((u32)f2b(b.w) << 16));
    } else {
        r = *(const uint4*)((const u16*)src + idx);
    }
    *(uint4*)dst = r;
}

// ---------------- dtype detect: n1_g == ones. bf16 -> u16[0]=0x3F80; f32 LE -> u16[0]=0 ----
__global__ void detect_dtype(const u16* __restrict__ n1g, int* __restrict__ flag) {
    *flag = (n1g[0] == 0) ? 1 : 0;
}

// ---------------- generic batched NT GEMM:  C (+)= act(scale * A @ W^T + bias) --------------
// A: [M,K] row-major (lda), W: [N,K] row-major (ldb); element offsets; per-batch via div/mod.
template <int OUTF32, int ACT, int TRANS, int ACC>
__global__ __launch_bounds__(256) void gemm_nt(
    const void* __restrict__ A, const void* __restrict__ B, const void* __restrict__ bias,
    void* __restrict__ Cv, int M, int N, int K, int lda, int ldb, int ldc, float scale,
    long aBase, long aDiv, long aOut, long aIn,
    long bBase, long bDiv, long bOut, long bIn,
    long cDiv, long cOut, long cIn,
    long biasBase, int aIsIn, int bIsIn, int biasIsIn, const int* __restrict__ flagp)
{
    const int dfl = *flagp;
    const int af = aIsIn ? dfl : 0;
    const int bfF = bIsIn ? dfl : 0;
    const int sf = biasIsIn ? dfl : 0;

    long bi = blockIdx.z;
    const long aOff = aBase + (bi / aDiv) * aOut + (bi % aDiv) * aIn;
    const long bOff = bBase + (bi / bDiv) * bOut + (bi % bDiv) * bIn;
    const long cOff = (bi / cDiv) * cOut + (bi % cDiv) * cIn;

    __shared__ u16 As[64][40];  // +8 pad
    __shared__ u16 Bs[64][40];

    const int tid = threadIdx.x;
    const int w = tid >> 6;
    const int lane = tid & 63;
    const int m0 = blockIdx.y * 64;
    const int n0 = blockIdx.x * 64;

    const int lr = tid >> 2;       // staging row 0..63
    const int lk = (tid & 3) * 8;  // staging k offset

    fx4 acc[4];
#pragma unroll
    for (int c = 0; c < 4; ++c)
#pragma unroll
        for (int r = 0; r < 4; ++r) acc[c][r] = 0.f;

    const int arow = m0 + lr;
    const int brow = n0 + lr;
    const bool aok = arow < M;
    const bool bok = brow < N;

    const int row16 = lane & 15;
    const int quad = lane >> 4;

    for (int k0 = 0; k0 < K; k0 += 32) {
        __syncthreads();
        stage8(&As[lr][lk], A, aOff + (long)arow * lda + k0 + lk, af, aok);
        stage8(&Bs[lr][lk], B, bOff + (long)brow * ldb + k0 + lk, bfF, bok);
        __syncthreads();
        bfx8 afr = *(const bfx8*)&As[w * 16 + row16][quad * 8];
#pragma unroll
        for (int c = 0; c < 4; ++c) {
            bfx8 bfr = *(const bfx8*)&Bs[c * 16 + row16][quad * 8];
            acc[c] = __builtin_amdgcn_mfma_f32_16x16x32_bf16(afr, bfr, acc[c], 0, 0, 0);
        }
    }

#pragma unroll
    for (int c = 0; c < 4; ++c) {
        int col = n0 + c * 16 + row16;
        float bvv = bias ? ldx(bias, biasBase + col, sf) : 0.f;
#pragma unroll
        for (int r = 0; r < 4; ++r) {
            int row = m0 + w * 16 + quad * 4 + r;
            if (row < M) {
                float v = acc[c][r] * scale + bvv;
                if (ACT == 1) v = gelu_(v);
                long idx = TRANS ? ((long)col * ldc + row) : ((long)row * ldc + col);
                if (OUTF32) {
                    ((float*)Cv)[cOff + idx] = v;
                } else {
                    if (ACC) v += b2f(((u16*)Cv)[cOff + idx]);
                    ((u16*)Cv)[cOff + idx] = f2b(v);
                }
            }
        }
    }
}

// ---------------- flash self-attention for ONE batch: S=1024, H=16, dh=64 ----------------
// QKV: [1024, 3072] bf16 internal. O in-place over the q slice (same-thread read/write).
__global__ __launch_bounds__(256) void attn_self(const u16* __restrict__ QKV, u16* __restrict__ O, int ldo)
{
    const int h = blockIdx.y;
    const u16* Qb = QKV + h * 64;
    const u16* Kb = Qb + 1024;
    const u16* Vb = Qb + 2048;
    u16* Ob = O + h * 64;
    const int tid = threadIdx.x;
    const int qi = blockIdx.x * 256 + tid;

    __shared__ float Ks[64][68];
    __shared__ float Vs[64][68];

    float4 q4[16];
    {
        const uint4* qp = (const uint4*)(Qb + (long)qi * 3072);
#pragma unroll
        for (int i = 0; i < 8; ++i) {
            uint4 u = qp[i];
            q4[2 * i]     = unpack4(u.x, u.y);
            q4[2 * i + 1] = unpack4(u.z, u.w);
        }
    }
    float4 acc[16];
#pragma unroll
    for (int i = 0; i < 16; ++i) { acc[i].x = 0.f; acc[i].y = 0.f; acc[i].z = 0.f; acc[i].w = 0.f; }
    float m = -__builtin_inff(), l = 0.f;

    const int sr = tid >> 2;
    const int scf = (tid & 3) * 16;

    for (int kt = 0; kt < 16; ++kt) {
        __syncthreads();
        {
            long krow = (long)(kt * 64 + sr);
            const uint4* kp = (const uint4*)(Kb + krow * 3072 + scf);
            uint4 u0 = kp[0], u1 = kp[1];
            float4* kd = (float4*)&Ks[sr][scf];
            kd[0] = unpack4(u0.x, u0.y); kd[1] = unpack4(u0.z, u0.w);
            kd[2] = unpack4(u1.x, u1.y); kd[3] = unpack4(u1.z, u1.w);
            const uint4* vp = (const uint4*)(Vb + krow * 3072 + scf);
            uint4 w0 = vp[0], w1 = vp[1];
            float4* vd = (float4*)&Vs[sr][scf];
            vd[0] = unpack4(w0.x, w0.y); vd[1] = unpack4(w0.z, w0.w);
            vd[2] = unpack4(w1.x, w1.y); vd[3] = unpack4(w1.z, w1.w);
        }
        __syncthreads();
#pragma unroll 4
        for (int kk = 0; kk < 64; ++kk) {
            const float4* kr = (const float4*)&Ks[kk][0];
            float s = 0.f;
#pragma unroll
            for (int i = 0; i < 16; ++i) {
                float4 kv = kr[i];
                s += q4[i].x * kv.x + q4[i].y * kv.y + q4[i].z * kv.z + q4[i].w * kv.w;
            }
            s *= 0.125f;
            float mn = fmaxf(m, s);
            if (mn > m) {
                float al = __expf(m - mn);
                l *= al;
#pragma unroll
                for (int i = 0; i < 16; ++i) { acc[i].x *= al; acc[i].y *= al; acc[i].z *= al; acc[i].w *= al; }
                m = mn;
            }
            float p = __expf(s - m);
            l += p;
            const float4* vr = (const float4*)&Vs[kk][0];
#pragma unroll
            for (int i = 0; i < 16; ++i) {
                float4 vv = vr[i];
                acc[i].x += p * vv.x; acc[i].y += p * vv.y; acc[i].z += p * vv.z; acc[i].w += p * vv.w;
            }
        }
    }
    float inv = 1.f / l;
    u32* op = (u32*)(Ob + (long)qi * ldo);
#pragma unroll
    for (int i = 0; i < 16; ++i) {
        float4 a = acc[i];
        op[2 * i]     = (u32)f2b(a.x * inv) | ((u32)f2b(a.y * inv) << 16);
        op[2 * i + 1] = (u32)f2b(a.z * inv) | ((u32)f2b(a.w * inv) << 16);
    }
}

// ---------------- in-place row softmax over bf16 (W = 512 or 1024) ----------------
__global__ __launch_bounds__(256) void softmax_inplace(u16* __restrict__ d, int W)
{
    long row = blockIdx.x;
    u16* r = d + row * W;
    int t = threadIdx.x;
    int n = W >> 8;
    float v[4];
    float mx = -1e30f;
    for (int i = 0; i < n; ++i) { v[i] = b2f(r[t + 256 * i]); mx = fmaxf(mx, v[i]); }
    __shared__ float red[256];
    red[t] = mx; __syncthreads();
    for (int s = 128; s > 0; s >>= 1) { if (t < s) red[t] = fmaxf(red[t], red[t + s]); __syncthreads(); }
    mx = red[0]; __syncthreads();
    float sum = 0.f;
    for (int i = 0; i < n; ++i) { v[i] = __expf(v[i] - mx); sum += v[i]; }
    red[t] = sum; __syncthreads();
    for (int s = 128; s > 0; s >>= 1) { if (t < s) red[t] += red[t + s]; __syncthreads(); }
    float inv = 1.f / red[0];
    for (int i = 0; i < n; ++i) r[t + 256 * i] = f2b(v[i] * inv);
}

// ---------------- residual add + LayerNorm, D=1024; o1 internal bf16 (may alias a); o2 = d_out ----
__global__ __launch_bounds__(256) void add_ln(const u16* __restrict__ a, const u16* __restrict__ rres,
                                              const void* __restrict__ g, const void* __restrict__ be,
                                              u16* __restrict__ o1, void* __restrict__ o2, long o2off,
                                              const int* __restrict__ flagp)
{
    const int f = *flagp;
    long row = blockIdx.x;
    int t = threadIdx.x;
    const u16* ar = a + row * 1024;
    const u16* rr = rres + row * 1024;
    float v[4];
#pragma unroll
    for (int i = 0; i < 4; ++i) { int j = t + 256 * i; v[i] = b2f(ar[j]) + b2f(rr[j]); }
    __shared__ float red[256];
    float s = v[0] + v[1] + v[2] + v[3];
    red[t] = s; __syncthreads();
    for (int k = 128; k > 0; k >>= 1) { if (t < k) red[t] += red[t + k]; __syncthreads(); }
    float mean = red[0] * (1.f / 1024.f);
    __syncthreads();
    float sq = 0.f;
#pragma unroll
    for (int i = 0; i < 4; ++i) { float d = v[i] - mean; sq += d * d; }
    red[t] = sq; __syncthreads();
    for (int k = 128; k > 0; k >>= 1) { if (t < k) red[t] += red[t + k]; __syncthreads(); }
    float rs = rsqrtf(red[0] * (1.f / 1024.f) + 1e-5f);
#pragma unroll
    for (int i = 0; i < 4; ++i) {
        int j = t + 256 * i;
        float y = (v[i] - mean) * rs * ldx(g, j, f) + ldx(be, j, f);
        o1[row * 1024 + j] = f2b(y);
        if (o2) stx(o2, o2off + row * 1024 + j, y, f);
    }
}

// ---------------- small pointwise kernels ----------------
__global__ __launch_bounds__(256) void build_cid(const void* __restrict__ cache, const void* __restrict__ lids,
                                                 u16* __restrict__ cid, const int* __restrict__ flagp)
{
    const int f = *flagp;
    long i = (long)blockIdx.x * 256 + threadIdx.x;
    if (i >= 4096L * 320) return;
    long row = i / 320, c = i % 320;
    float v = (c < 256) ? ldx(cache, row * 256 + c, f) : ldx(lids, (row & 511) * 64 + (c - 256), f);
    cid[i] = f2b(v);
}

__global__ __launch_bounds__(256) void fill_ctx_le(const void* __restrict__ le, u16* __restrict__ ctxcat,
                                                   const int* __restrict__ flagp)
{
    const int f = *flagp;
    long i = (long)blockIdx.x * 256 + threadIdx.x;
    if (i >= 8192L * 64) return;
    long row = i >> 6, j = i & 63;
    ctxcat[row * 320 + 256 + j] = f2b(ldx(le, j, f));
}

// xf = sigmoid(gate)*x + (1-sigmoid(gate))*context ; in-place over gl
__global__ __launch_bounds__(256) void fusion(const void* __restrict__ x, const u16* __restrict__ ctx,
                                              u16* __restrict__ gl_xf, const int* __restrict__ flagp)
{
    const int f = *flagp;
    long i = (long)blockIdx.x * 256 + threadIdx.x;  // 8192*1024 exact
    float gv = sigmoid_(b2f(gl_xf[i]));
    float xv = ldx(x, i, f);
    float cv = b2f(ctx[i]);
    gl_xf[i] = f2b(gv * xv + (1.f - gv) * cv);
}

__global__ __launch_bounds__(256) void cast_pat(const float* __restrict__ pf, u16* __restrict__ pb,
                                                void* __restrict__ pout, long poff,
                                                const int* __restrict__ flagp)
{
    const int f = *flagp;
    long i = (long)blockIdx.x * 256 + threadIdx.x;
    if (i >= 131072L) return;
    float v = pf[i];
    pb[i] = f2b(v);
    stx(pout, poff + i, v, f);
}

// ---------------- pattern attention PV for ONE batch ----------------
__global__ __launch_bounds__(64) void pat_pv(const u16* __restrict__ patp, const u16* __restrict__ kv,
                                             u16* __restrict__ opat)
{
    int qi = blockIdx.x, h = blockIdx.y, t = threadIdx.x;
    const u16* prow = patp + ((long)(h * 16 + qi)) * 1024;
    const u16* v = kv + 1024 + h * 64 + t;
    float o = 0.f;
#pragma unroll 4
    for (int key = 0; key < 1024; ++key) o += b2f(prow[key]) * b2f(v[(long)key * 2048]);
    opat[(long)qi * 1024 + h * 64 + t] = f2b(o);
}

// ---------------- selection head ----------------
__global__ __launch_bounds__(64) void final_head(const u16* __restrict__ patb, const float* __restrict__ learned,
                                                 const float* __restrict__ content, const void* __restrict__ gum,
                                                 const void* __restrict__ gw, const void* __restrict__ gb,
                                                 const void* __restrict__ anw, const void* __restrict__ anb,
                                                 void* __restrict__ outp, long oSC, long oSLOT, long oSOFT, long oAL,
                                                 const int* __restrict__ flagp)
{
    const int f = *flagp;
    int row = blockIdx.x;  // 0..127
    int t = threadIdx.x;   // 0..63
    float pa = 0.f, ps = 0.f;
    for (int j = t; j < 1024; j += 64) {
        float p = b2f(patb[(long)row * 1024 + j]);
        pa += p * ldx(anw, j, f);
        ps += p * ldx(gw, j, f);
    }
#pragma unroll
    for (int off = 32; off > 0; off >>= 1) { pa += __shfl_xor(pa, off); ps += __shfl_xor(ps, off); }
    float alpha = sigmoid_(pa + ldx(anb, 0, f));
    float score = sigmoid_(ps + ldx(gb, 0, f));
    float logit = alpha * learned[row * 64 + t] + (1.f - alpha) * content[row * 64 + t];
    float u = ldx(gum, row * 64 + t, f);
    float inner = -logf(u + 1e-8f) + 1e-8f;
    inner = fmaxf(inner, 1e-20f);
    float gg = -logf(inner);
    float l1 = logit + gg, l2 = logit;
    float m1 = l1, m2 = l2;
#pragma unroll
    for (int off = 32; off > 0; off >>= 1) { m1 = fmaxf(m1, __shfl_xor(m1, off)); m2 = fmaxf(m2, __shfl_xor(m2, off)); }
    float e1 = __expf(l1 - m1), e2 = __expf(l2 - m2);
    float s1 = e1, s2 = e2;
#pragma unroll
    for (int off = 32; off > 0; off >>= 1) { s1 += __shfl_xor(s1, off); s2 += __shfl_xor(s2, off); }
    stx(outp, oSLOT + row * 64 + t, e1 / s1, f);
    stx(outp, oSOFT + row * 64 + t, e2 / s2, f);
    if (t == 0) { stx(outp, oSC + row, score, f); stx(outp, oAL + row, alpha, f); }
}

// ---------------- host-side GEMM wrapper ----------------
static void launch_gemm(hipStream_t st, int outf32, int act, int trans, int acc,
                        const void* A, const void* B, const void* bias, void* C,
                        int M, int N, int K, int lda, int ldb, int ldc, float scale, int batch,
                        long aBase, long aD, long aO, long aI,
                        long bBase, long bD, long bO, long bI,
                        long cD, long cO, long cI,
                        long biasBase, int aIsIn, int bIsIn, int biasIsIn, const int* flagp)
{
    dim3 g(N / 64, (M + 63) / 64, batch);
#define PASS A, B, bias, C, M, N, K, lda, ldb, ldc, scale, aBase, aD, aO, aI, bBase, bD, bO, bI, \
             cD, cO, cI, biasBase, aIsIn, bIsIn, biasIsIn, flagp
    if (outf32)      gemm_nt<1, 0, 0, 0><<<g, 256, 0, st>>>(PASS);
    else if (act)    gemm_nt<0, 1, 0, 0><<<g, 256, 0, st>>>(PASS);
    else if (trans)  gemm_nt<0, 0, 1, 0><<<g, 256, 0, st>>>(PASS);
    else if (acc)    gemm_nt<0, 0, 0, 1><<<g, 256, 0, st>>>(PASS);
    else             gemm_nt<0, 0, 0, 0><<<g, 256, 0, st>>>(PASS);
#undef PASS
}

// ---------------- workspace layout (bytes); peak ~38 MiB + 4B flag ----------------
#define WS_CID     0L           // S1-4   (2.62 MB)
#define WS_QB      2621440L     // S2-5   (4.19 MB)
#define WS_KKB     6815744L     // S3-5   (2.10 MB)
#define WS_VVT     8912896L     // S4-7   (2.10 MB)
#define WS_SC      11010048L    // S5-7   (8.39 MB, in-place softmax S6)
#define WS_CTXCAT  0L           // S7-10  (5.24 MB) over cid/qb (dead after S5)
#define WS_CONTEXT 16777216L    // S10-12 (16.78 MB) over sc-tail (dead after S7)
#define WS_XF      0L           // S11-S21: gate logits -> xf -> xf2 -> y (16.78 MB)
#define WS_QKVB    33554432L    // S13-15 per-batch (6.29 MB); attn O in-place in q-slice
#define WS_PROJ    16777216L    // S15-16 (16.78 MB) over context (dead after S12)
#define WS_FFN1C   16777216L    // S17-18 per-chunk (16.78 MB) over proj (dead after S16)
#define WS_FFN2C   33554432L    // S18-19 per-chunk (4.19 MB) over qkvb (dead after S15)
#define WS_KVPATB  16777216L    // S21-24 per-batch (4.19 MB) over ffn1c (dead)
#define WS_QPAT    20971520L    // S20-22 (32 KB)
#define WS_PATSCB  21004288L    // S22-24 per-batch (0.52 MB, in-place softmax)
#define WS_OPAT    21528576L    // S24-25 (0.26 MB)
#define WS_PATF32  21790720L    // S25-26 f32 (0.52 MB)
#define WS_PATB    22315008L    // S26-31 (0.26 MB)
#define WS_LEARN   22577152L    // S27-31 f32 (32 KB)
#define WS_SQP     22609920L    // S28-30 (64 KB)
#define WS_SKE     22675456L    // S29-30 (32 KB)
#define WS_CONT    22708224L    // S30-31 f32 (32 KB)
#define WS_FLAG    39845888L    // dtype flag (int), never overwritten

// output offsets (elements)
#define OUT_Y      0L
#define OUT_PAT    8388608L
#define OUT_SCORES 8519680L
#define OUT_SLOT   8519808L
#define OUT_SOFT   8528000L
#define OUT_ALPHA  8536192L

extern "C" void kernel_launch(void* const* d_in, const int* in_sizes, int n_in,
                              void* d_out, int out_size, void* d_ws, size_t ws_size,
                              hipStream_t stream)
{
    const void* x     = d_in[0];
    const void* cache = d_in[1];
    const void* slote = d_in[2];
    const void* lids  = d_in[3];
    const void* gum   = d_in[4];
    const void* le    = d_in[5];
    const void* awqkv = d_in[6];
    const void* abqkv = d_in[7];
    const void* awo   = d_in[8];
    const void* abo   = d_in[9];
    const void* pwqkv = d_in[10];
    const void* pbqkv = d_in[11];
    const void* pwo   = d_in[12];
    const void* pbo   = d_in[13];
    const void* pq    = d_in[14];
    const void* fw1   = d_in[15];
    const void* fb1   = d_in[16];
    const void* fw2   = d_in[17];
    const void* fb2   = d_in[18];
    const void* n1g   = d_in[19];
    const void* n1b   = d_in[20];
    const void* n2g   = d_in[21];
    const void* n2b   = d_in[22];
    const void* gw    = d_in[23];
    const void* gb    = d_in[24];
    const void* selw  = d_in[25];
    const void* selb  = d_in[26];
    const void* sqw   = d_in[27];
    const void* sqb   = d_in[28];
    const void* skw   = d_in[29];
    const void* skb   = d_in[30];
    const void* anw   = d_in[31];
    const void* anb   = d_in[32];
    const void* decw  = d_in[33];
    const void* decb  = d_in[34];
    const void* cqw   = d_in[35];
    const void* cqb   = d_in[36];
    const void* ckw   = d_in[37];
    const void* ckb   = d_in[38];
    const void* cvw   = d_in[39];
    const void* cvb   = d_in[40];
    const void* fgw   = d_in[41];
    const void* fgb   = d_in[42];

    char* ws = (char*)d_ws;
    auto W  = [&](long off) { return (u16*)(ws + off); };
    auto Wf = [&](long off) { return (float*)(ws + off); };
    int* flg = (int*)(ws + WS_FLAG);

    // S0) detect input/output dtype (f32 vs bf16) from n1_g == ones
    detect_dtype<<<1, 1, 0, stream>>>((const u16*)n1g, flg);
    // S1) cid = concat(cache, layer_ids)  (bf16 internal)
    build_cid<<<dim3((4096 * 320 + 255) / 256), 256, 0, stream>>>(cache, lids, W(WS_CID), flg);
    // S2) q = x @ cq_w^T + cq_b
    launch_gemm(stream, 0, 0, 0, 0, x, cqw, cqb, W(WS_QB), 8192, 256, 1024, 1024, 1024, 256, 1.f, 1,
                0, 1, 0, 0, 0, 1, 0, 0, 1, 0, 0, 0, 1, 1, 1, flg);
    // S3) kk = cid @ ck_w^T + ck_b
    launch_gemm(stream, 0, 0, 0, 0, W(WS_CID), ckw, ckb, W(WS_KKB), 4096, 256, 320, 320, 320, 256, 1.f, 1,
                0, 1, 0, 0, 0, 1, 0, 0, 1, 0, 0, 0, 0, 1, 1, flg);
    // S4) vvT[b] = (cid[b] @ cv_w^T + cv_b)^T
    launch_gemm(stream, 0, 0, 1, 0, W(WS_CID), cvw, cvb, W(WS_VVT), 512, 256, 320, 320, 320, 512, 1.f, 8,
                0, 1, 163840, 0, 0, 1, 0, 0, 1, 131072, 0, 0, 0, 1, 1, flg);
    // S5) sc[b] = q[b] @ kk[b]^T / 16  (bf16)
    launch_gemm(stream, 0, 0, 0, 0, W(WS_QB), W(WS_KKB), nullptr, W(WS_SC), 1024, 512, 256, 256, 256, 512,
                0.0625f, 8, 0, 1, 262144, 0, 0, 1, 131072, 0, 1, 524288, 0, 0, 0, 0, 0, flg);
    // S6) softmax over 512, in place
    softmax_inplace<<<8192, 256, 0, stream>>>(W(WS_SC), 512);
    // S7) ctx[b] = attn[b] @ vvT[b]^T -> ctxcat cols 0..255
    launch_gemm(stream, 0, 0, 0, 0, W(WS_SC), W(WS_VVT), nullptr, W(WS_CTXCAT), 1024, 256, 512, 512, 512, 320,
                1.f, 8, 0, 1, 524288, 0, 0, 1, 131072, 0, 1, 327680, 0, 0, 0, 0, 0, flg);
    // S8) ctxcat cols 256..319 = layer_embed
    fill_ctx_le<<<dim3((8192 * 64 + 255) / 256), 256, 0, stream>>>(le, W(WS_CTXCAT), flg);
    // S10) context = ctxcat @ dec_w^T + dec_b
    launch_gemm(stream, 0, 0, 0, 0, W(WS_CTXCAT), decw, decb, W(WS_CONTEXT), 8192, 1024, 320, 320, 320, 1024,
                1.f, 1, 0, 1, 0, 0, 0, 1, 0, 0, 1, 0, 0, 0, 0, 1, 1, flg);
    // S11a) gate logits = x @ fg_w[:, :1024]^T + fg_b
    launch_gemm(stream, 0, 0, 0, 0, x, fgw, fgb, W(WS_XF), 8192, 1024, 1024, 1024, 2048, 1024, 1.f, 1,
                0, 1, 0, 0, 0, 1, 0, 0, 1, 0, 0, 0, 1, 1, 1, flg);
    // S11b) gate logits += context @ fg_w[:, 1024:]^T
    launch_gemm(stream, 0, 0, 0, 1, W(WS_CONTEXT), fgw, nullptr, W(WS_XF), 8192, 1024, 1024, 1024, 2048, 1024,
                1.f, 1, 0, 1, 0, 0, 1024, 1, 0, 0, 1, 0, 0, 0, 0, 1, 0, flg);
    // S12) xf = sigmoid(gate)*x + (1-sigmoid)*context  (in place)
    fusion<<<32768, 256, 0, stream>>>(x, W(WS_CONTEXT), W(WS_XF), flg);
    // S13-15) per-batch: qkv -> flash attention (in-place O) -> out proj
    for (int b = 0; b < 8; ++b) {
        launch_gemm(stream, 0, 0, 0, 0, W(WS_XF) + (long)b * 1048576, awqkv, abqkv, W(WS_QKVB),
                    1024, 3072, 1024, 1024, 1024, 3072, 1.f, 1,
                    0, 1, 0, 0, 0, 1, 0, 0, 1, 0, 0, 0, 0, 1, 1, flg);
        attn_self<<<dim3(4, 16, 1), 256, 0, stream>>>(W(WS_QKVB), W(WS_QKVB), 3072);
        launch_gemm(stream, 0, 0, 0, 0, W(WS_QKVB), awo, abo, W(WS_PROJ) + (long)b * 1048576,
                    1024, 1024, 1024, 3072, 1024, 1024, 1.f, 1,
                    0, 1, 0, 0, 0, 1, 0, 0, 1, 0, 0, 0, 0, 1, 1, flg);
    }
    // S16) xf2 = LN(xf + proj)  (in place over xf)
    add_ln<<<8192, 256, 0, stream>>>(W(WS_XF), W(WS_PROJ), n1g, n1b, W(WS_XF), nullptr, 0, flg);
    // S17-19) FFN in 4 row-chunks of 2048; y = LN(xf2 + ffn2) in place + to out
    for (int c = 0; c < 4; ++c) {
        u16* xf2c = W(WS_XF) + (long)c * 2048 * 1024;
        launch_gemm(stream, 0, 1, 0, 0, xf2c, fw1, fb1, W(WS_FFN1C), 2048, 4096, 1024, 1024, 1024, 4096,
                    1.f, 1, 0, 1, 0, 0, 0, 1, 0, 0, 1, 0, 0, 0, 0, 1, 1, flg);
        launch_gemm(stream, 0, 0, 0, 0, W(WS_FFN1C), fw2, fb2, W(WS_FFN2C), 2048, 1024, 4096, 4096, 4096, 1024,
                    1.f, 1, 0, 1, 0, 0, 0, 1, 0, 0, 1, 0, 0, 0, 0, 1, 1, flg);
        add_ln<<<2048, 256, 0, stream>>>(xf2c, W(WS_FFN2C), n2g, n2b, xf2c, d_out,
                                         OUT_Y + (long)c * 2048 * 1024, flg);
    }
    // S20) qpat = pattern_queries @ wq_pat^T + bq_pat
    launch_gemm(stream, 0, 0, 0, 0, pq, pwqkv, pbqkv, W(WS_QPAT), 16, 1024, 1024, 1024, 1024, 1024, 1.f, 1,
                0, 1, 0, 0, 0, 1, 0, 0, 1, 0, 0, 0, 1, 1, 1, flg);
    // S21-24) per-batch pattern attention
    for (int b = 0; b < 8; ++b) {
        const u16* yb = W(WS_XF) + (long)b * 1048576;
        launch_gemm(stream, 0, 0, 0, 0, yb, pwqkv, pbqkv, W(WS_KVPATB), 1024, 2048, 1024, 1024, 1024, 2048,
                    1.f, 1, 0, 1, 0, 0, 1048576, 1, 0, 0, 1, 0, 0, 1024, 0, 1, 1, flg);
        launch_gemm(stream, 0, 0, 0, 0, W(WS_QPAT), W(WS_KVPATB), nullptr, W(WS_PATSCB), 16, 1024, 64,
                    1024, 2048, 1024, 0.125f, 16,
                    0, 16, 0, 64, 0, 16, 0, 64, 1, 16384, 0, 0, 0, 0, 0, flg);
        softmax_inplace<<<256, 256, 0, stream>>>(W(WS_PATSCB), 1024);
        pat_pv<<<dim3(16, 16, 1), 64, 0, stream>>>(W(WS_PATSCB), W(WS_KVPATB), W(WS_OPAT) + (long)b * 16384);
    }
    // S25) patterns = opat @ pat_wo^T + pat_bo (f32)
    launch_gemm(stream, 1, 0, 0, 0, W(WS_OPAT), pwo, pbo, Wf(WS_PATF32), 128, 1024, 1024, 1024, 1024, 1024,
                1.f, 1, 0, 1, 0, 0, 0, 1, 0, 0, 1, 0, 0, 0, 0, 1, 1, flg);
    // S26) cast patterns -> ws bf16 + d_out
    cast_pat<<<512, 256, 0, stream>>>(Wf(WS_PATF32), W(WS_PATB), d_out, OUT_PAT, flg);
    // S27) learned = patterns @ sel_w^T + sel_b (f32)
    launch_gemm(stream, 1, 0, 0, 0, W(WS_PATB), selw, selb, Wf(WS_LEARN), 128, 64, 1024, 1024, 1024, 64,
                1.f, 1, 0, 1, 0, 0, 0, 1, 0, 0, 1, 0, 0, 0, 0, 1, 1, flg);
    // S28) sqp = patterns @ sq_w^T + sq_b
    launch_gemm(stream, 0, 0, 0, 0, W(WS_PATB), sqw, sqb, W(WS_SQP), 128, 256, 1024, 1024, 1024, 256, 1.f, 1,
                0, 1, 0, 0, 0, 1, 0, 0, 1, 0, 0, 0, 0, 1, 1, flg);
    // S29) ske = slot_embeddings @ sk_w^T + sk_b
    launch_gemm(stream, 0, 0, 0, 0, slote, skw, skb, W(WS_SKE), 64, 256, 256, 256, 256, 256, 1.f, 1,
                0, 1, 0, 0, 0, 1, 0, 0, 1, 0, 0, 0, 1, 1, 1, flg);
    // S30) content = sqp @ ske^T / 16 (f32)
    launch_gemm(stream, 1, 0, 0, 0, W(WS_SQP), W(WS_SKE), nullptr, Wf(WS_CONT), 128, 64, 256, 256, 256, 64,
                0.0625f, 1, 0, 1, 0, 0, 0, 1, 0, 0, 1, 0, 0, 0, 0, 0, 0, flg);
    // S31) selection head outputs
    final_head<<<128, 64, 0, stream>>>(W(WS_PATB), Wf(WS_LEARN), Wf(WS_CONT), gum, gw, gb, anw, anb,
                                       d_out, OUT_SCORES, OUT_SLOT, OUT_SOFT, OUT_ALPHA, flg);
}

// Round 5
// 2325.814 us; speedup vs baseline: 3.7849x; 3.7849x over previous
//
#include <hip/hip_runtime.h>
#include <math.h>

typedef unsigned short u16;
typedef unsigned int u32;
typedef __bf16 bfx8 __attribute__((ext_vector_type(8)));
typedef float fx4 __attribute__((ext_vector_type(4)));

// ---------------- numeric helpers ----------------
__device__ __forceinline__ float b2f(u16 v) { return __uint_as_float(((u32)v) << 16); }
__device__ __forceinline__ u16 f2b(float f) {  // round-to-nearest-even
    u32 u = __float_as_uint(f);
    u32 lsb = (u >> 16) & 1u;
    u += 0x7fffu + lsb;
    return (u16)(u >> 16);
}
__device__ __forceinline__ float4 unpack4(u32 a, u32 b) {
    float4 r;
    r.x = __uint_as_float(a << 16);
    r.y = __uint_as_float(a & 0xffff0000u);
    r.z = __uint_as_float(b << 16);
    r.w = __uint_as_float(b & 0xffff0000u);
    return r;
}
__device__ __forceinline__ float sigmoid_(float x) { return 1.f / (1.f + __expf(-x)); }
__device__ __forceinline__ float gelu_(float x) { return 0.5f * x * (1.f + erff(x * 0.7071067811865475f)); }

// dtype-adaptive scalar load/store: f==1 -> buffer is float32, else bf16
__device__ __forceinline__ float ldx(const void* p, long i, int f) {
    return f ? ((const float*)p)[i] : b2f(((const u16*)p)[i]);
}
__device__ __forceinline__ void stx(void* p, long i, float v, int f) {
    if (f) ((float*)p)[i] = v;
    else ((u16*)p)[i] = f2b(v);
}
// stage 8 consecutive elements into LDS as bf16
__device__ __forceinline__ void stage8(u16* dst, const void* src, long idx, int f, bool ok) {
    uint4 r;
    if (!ok) {
        r = make_uint4(0u, 0u, 0u, 0u);
    } else if (f) {
        const float* p = (const float*)src + idx;
        float4 a = *(const float4*)p;
        float4 b = *(const float4*)(p + 4);
        r = make_uint4((u32)f2b(a.x) | ((u32)f2b(a.y) << 16),
                       (u32)f2b(a.z) | ((u32)f2b(a.w) << 16),
                       (u32)f2b(b.x) | ((u32)f2b(b.y) << 16),
                       (u32)f2b(b.z) | ((u32)f2b(b.w) << 16));
    } else {
        r = *(const uint4*)((const u16*)src + idx);
    }
    *(uint4*)dst = r;
}

// ---------------- dtype detect: n1_g == ones. bf16 -> u16[0]=0x3F80; f32 LE -> u16[0]=0 ----
__global__ void detect_dtype(const u16* __restrict__ n1g, int* __restrict__ flag) {
    *flag = (n1g[0] == 0) ? 1 : 0;
}

// ---------------- generic batched NT GEMM:  C (+)= act(scale * A @ W^T + bias) --------------
template <int OUTF32, int ACT, int TRANS, int ACC>
__global__ __launch_bounds__(256) void gemm_nt(
    const void* __restrict__ A, const void* __restrict__ B, const void* __restrict__ bias,
    void* __restrict__ Cv, int M, int N, int K, int lda, int ldb, int ldc, float scale,
    long aBase, long aDiv, long aOut, long aIn,
    long bBase, long bDiv, long bOut, long bIn,
    long cDiv, long cOut, long cIn,
    long biasBase, int aIsIn, int bIsIn, int biasIsIn, const int* __restrict__ flagp)
{
    const int dfl = *flagp;
    const int af = aIsIn ? dfl : 0;
    const int bfF = bIsIn ? dfl : 0;
    const int sf = biasIsIn ? dfl : 0;

    long bi = blockIdx.z;
    const long aOff = aBase + (bi / aDiv) * aOut + (bi % aDiv) * aIn;
    const long bOff = bBase + (bi / bDiv) * bOut + (bi % bDiv) * bIn;
    const long cOff = (bi / cDiv) * cOut + (bi % cDiv) * cIn;

    __shared__ u16 As[64][40];
    __shared__ u16 Bs[64][40];

    const int tid = threadIdx.x;
    const int w = tid >> 6;
    const int lane = tid & 63;
    const int m0 = blockIdx.y * 64;
    const int n0 = blockIdx.x * 64;

    const int lr = tid >> 2;
    const int lk = (tid & 3) * 8;

    fx4 acc[4];
#pragma unroll
    for (int c = 0; c < 4; ++c)
#pragma unroll
        for (int r = 0; r < 4; ++r) acc[c][r] = 0.f;

    const int arow = m0 + lr;
    const int brow = n0 + lr;
    const bool aok = arow < M;
    const bool bok = brow < N;

    const int row16 = lane & 15;
    const int quad = lane >> 4;

    for (int k0 = 0; k0 < K; k0 += 32) {
        __syncthreads();
        stage8(&As[lr][lk], A, aOff + (long)arow * lda + k0 + lk, af, aok);
        stage8(&Bs[lr][lk], B, bOff + (long)brow * ldb + k0 + lk, bfF, bok);
        __syncthreads();
        bfx8 afr = *(const bfx8*)&As[w * 16 + row16][quad * 8];
#pragma unroll
        for (int c = 0; c < 4; ++c) {
            bfx8 bfr = *(const bfx8*)&Bs[c * 16 + row16][quad * 8];
            acc[c] = __builtin_amdgcn_mfma_f32_16x16x32_bf16(afr, bfr, acc[c], 0, 0, 0);
        }
    }

#pragma unroll
    for (int c = 0; c < 4; ++c) {
        int col = n0 + c * 16 + row16;
        float bvv = bias ? ldx(bias, biasBase + col, sf) : 0.f;
#pragma unroll
        for (int r = 0; r < 4; ++r) {
            int row = m0 + w * 16 + quad * 4 + r;
            if (row < M) {
                float v = acc[c][r] * scale + bvv;
                if (ACT == 1) v = gelu_(v);
                long idx = TRANS ? ((long)col * ldc + row) : ((long)row * ldc + col);
                if (OUTF32) {
                    ((float*)Cv)[cOff + idx] = v;
                } else {
                    if (ACC) v += b2f(((u16*)Cv)[cOff + idx]);
                    ((u16*)Cv)[cOff + idx] = f2b(v);
                }
            }
        }
    }
}

// ---------------- flash self-attention: S=1024, H=16, dh=64; batch via blockIdx.z ----------------
// QKV rows [1024,3072] per batch at QKV + z*bStride. O in-place over the q slice.
__global__ __launch_bounds__(256) void attn_self(const u16* __restrict__ QKV, u16* __restrict__ O,
                                                 int ldo, long bStride)
{
    const int h = blockIdx.y;
    const long zoff = (long)blockIdx.z * bStride;
    const u16* Qb = QKV + zoff + h * 64;
    const u16* Kb = Qb + 1024;
    const u16* Vb = Qb + 2048;
    u16* Ob = O + zoff + h * 64;
    const int tid = threadIdx.x;
    const int qi = blockIdx.x * 256 + tid;

    __shared__ float Ks[64][68];
    __shared__ float Vs[64][68];

    float4 q4[16];
    {
        const uint4* qp = (const uint4*)(Qb + (long)qi * 3072);
#pragma unroll
        for (int i = 0; i < 8; ++i) {
            uint4 u = qp[i];
            q4[2 * i]     = unpack4(u.x, u.y);
            q4[2 * i + 1] = unpack4(u.z, u.w);
        }
    }
    float4 acc[16];
#pragma unroll
    for (int i = 0; i < 16; ++i) { acc[i].x = 0.f; acc[i].y = 0.f; acc[i].z = 0.f; acc[i].w = 0.f; }
    float m = -__builtin_inff(), l = 0.f;

    const int sr = tid >> 2;
    const int scf = (tid & 3) * 16;

    for (int kt = 0; kt < 16; ++kt) {
        __syncthreads();
        {
            long krow = (long)(kt * 64 + sr);
            const uint4* kp = (const uint4*)(Kb + krow * 3072 + scf);
            uint4 u0 = kp[0], u1 = kp[1];
            float4* kd = (float4*)&Ks[sr][scf];
            kd[0] = unpack4(u0.x, u0.y); kd[1] = unpack4(u0.z, u0.w);
            kd[2] = unpack4(u1.x, u1.y); kd[3] = unpack4(u1.z, u1.w);
            const uint4* vp = (const uint4*)(Vb + krow * 3072 + scf);
            uint4 w0 = vp[0], w1 = vp[1];
            float4* vd = (float4*)&Vs[sr][scf];
            vd[0] = unpack4(w0.x, w0.y); vd[1] = unpack4(w0.z, w0.w);
            vd[2] = unpack4(w1.x, w1.y); vd[3] = unpack4(w1.z, w1.w);
        }
        __syncthreads();
#pragma unroll 4
        for (int kk = 0; kk < 64; ++kk) {
            const float4* kr = (const float4*)&Ks[kk][0];
            float s = 0.f;
#pragma unroll
            for (int i = 0; i < 16; ++i) {
                float4 kv = kr[i];
                s += q4[i].x * kv.x + q4[i].y * kv.y + q4[i].z * kv.z + q4[i].w * kv.w;
            }
            s *= 0.125f;
            float mn = fmaxf(m, s);
            if (mn > m) {
                float al = __expf(m - mn);
                l *= al;
#pragma unroll
                for (int i = 0; i < 16; ++i) { acc[i].x *= al; acc[i].y *= al; acc[i].z *= al; acc[i].w *= al; }
                m = mn;
            }
            float p = __expf(s - m);
            l += p;
            const float4* vr = (const float4*)&Vs[kk][0];
#pragma unroll
            for (int i = 0; i < 16; ++i) {
                float4 vv = vr[i];
                acc[i].x += p * vv.x; acc[i].y += p * vv.y; acc[i].z += p * vv.z; acc[i].w += p * vv.w;
            }
        }
    }
    float inv = 1.f / l;
    u32* op = (u32*)(Ob + (long)qi * ldo);
#pragma unroll
    for (int i = 0; i < 16; ++i) {
        float4 a = acc[i];
        op[2 * i]     = (u32)f2b(a.x * inv) | ((u32)f2b(a.y * inv) << 16);
        op[2 * i + 1] = (u32)f2b(a.z * inv) | ((u32)f2b(a.w * inv) << 16);
    }
}

// ---------------- in-place row softmax over bf16 (W = 512 or 1024) ----------------
__global__ __launch_bounds__(256) void softmax_inplace(u16* __restrict__ d, int W)
{
    long row = blockIdx.x;
    u16* r = d + row * W;
    int t = threadIdx.x;
    int n = W >> 8;
    float v[4];
    float mx = -1e30f;
    for (int i = 0; i < n; ++i) { v[i] = b2f(r[t + 256 * i]); mx = fmaxf(mx, v[i]); }
    __shared__ float red[256];
    red[t] = mx; __syncthreads();
    for (int s = 128; s > 0; s >>= 1) { if (t < s) red[t] = fmaxf(red[t], red[t + s]); __syncthreads(); }
    mx = red[0]; __syncthreads();
    float sum = 0.f;
    for (int i = 0; i < n; ++i) { v[i] = __expf(v[i] - mx); sum += v[i]; }
    red[t] = sum; __syncthreads();
    for (int s = 128; s > 0; s >>= 1) { if (t < s) red[t] += red[t + s]; __syncthreads(); }
    float inv = 1.f / red[0];
    for (int i = 0; i < n; ++i) r[t + 256 * i] = f2b(v[i] * inv);
}

// ---------------- residual add + LayerNorm, D=1024; o1 internal bf16 (may alias a); o2 = d_out ----
__global__ __launch_bounds__(256) void add_ln(const u16* __restrict__ a, const u16* __restrict__ rres,
                                              const void* __restrict__ g, const void* __restrict__ be,
                                              u16* __restrict__ o1, void* __restrict__ o2, long o2off,
                                              const int* __restrict__ flagp)
{
    const int f = *flagp;
    long row = blockIdx.x;
    int t = threadIdx.x;
    const u16* ar = a + row * 1024;
    const u16* rr = rres + row * 1024;
    float v[4];
#pragma unroll
    for (int i = 0; i < 4; ++i) { int j = t + 256 * i; v[i] = b2f(ar[j]) + b2f(rr[j]); }
    __shared__ float red[256];
    float s = v[0] + v[1] + v[2] + v[3];
    red[t] = s; __syncthreads();
    for (int k = 128; k > 0; k >>= 1) { if (t < k) red[t] += red[t + k]; __syncthreads(); }
    float mean = red[0] * (1.f / 1024.f);
    __syncthreads();
    float sq = 0.f;
#pragma unroll
    for (int i = 0; i < 4; ++i) { float d = v[i] - mean; sq += d * d; }
    red[t] = sq; __syncthreads();
    for (int k = 128; k > 0; k >>= 1) { if (t < k) red[t] += red[t + k]; __syncthreads(); }
    float rs = rsqrtf(red[0] * (1.f / 1024.f) + 1e-5f);
#pragma unroll
    for (int i = 0; i < 4; ++i) {
        int j = t + 256 * i;
        float y = (v[i] - mean) * rs * ldx(g, j, f) + ldx(be, j, f);
        o1[row * 1024 + j] = f2b(y);
        if (o2) stx(o2, o2off + row * 1024 + j, y, f);
    }
}

// ---------------- small pointwise kernels ----------------
__global__ __launch_bounds__(256) void build_cid(const void* __restrict__ cache, const void* __restrict__ lids,
                                                 u16* __restrict__ cid, const int* __restrict__ flagp)
{
    const int f = *flagp;
    long i = (long)blockIdx.x * 256 + threadIdx.x;
    if (i >= 4096L * 320) return;
    long row = i / 320, c = i % 320;
    float v = (c < 256) ? ldx(cache, row * 256 + c, f) : ldx(lids, (row & 511) * 64 + (c - 256), f);
    cid[i] = f2b(v);
}

__global__ __launch_bounds__(256) void fill_ctx_le(const void* __restrict__ le, u16* __restrict__ ctxcat,
                                                   const int* __restrict__ flagp)
{
    const int f = *flagp;
    long i = (long)blockIdx.x * 256 + threadIdx.x;
    if (i >= 8192L * 64) return;
    long row = i >> 6, j = i & 63;
    ctxcat[row * 320 + 256 + j] = f2b(ldx(le, j, f));
}

// xf = sigmoid(gate)*x + (1-sigmoid(gate))*context ; in-place over gl
__global__ __launch_bounds__(256) void fusion(const void* __restrict__ x, const u16* __restrict__ ctx,
                                              u16* __restrict__ gl_xf, const int* __restrict__ flagp)
{
    const int f = *flagp;
    long i = (long)blockIdx.x * 256 + threadIdx.x;
    float gv = sigmoid_(b2f(gl_xf[i]));
    float xv = ldx(x, i, f);
    float cv = b2f(ctx[i]);
    gl_xf[i] = f2b(gv * xv + (1.f - gv) * cv);
}

__global__ __launch_bounds__(256) void cast_pat(const float* __restrict__ pf, u16* __restrict__ pb,
                                                void* __restrict__ pout, long poff,
                                                const int* __restrict__ flagp)
{
    const int f = *flagp;
    long i = (long)blockIdx.x * 256 + threadIdx.x;
    if (i >= 131072L) return;
    float v = pf[i];
    pb[i] = f2b(v);
    stx(pout, poff + i, v, f);
}

// ---------------- pattern attention PV; batch via blockIdx.z with strides ----------------
__global__ __launch_bounds__(64) void pat_pv(const u16* __restrict__ patp, const u16* __restrict__ kv,
                                             u16* __restrict__ opat, long pStride, long kvStride, long oStride)
{
    int qi = blockIdx.x, h = blockIdx.y, z = blockIdx.z, t = threadIdx.x;
    const u16* prow = patp + (long)z * pStride + ((long)(h * 16 + qi)) * 1024;
    const u16* v = kv + (long)z * kvStride + 1024 + h * 64 + t;
    float o = 0.f;
#pragma unroll 4
    for (int key = 0; key < 1024; ++key) o += b2f(prow[key]) * b2f(v[(long)key * 2048]);
    opat[(long)z * oStride + (long)qi * 1024 + h * 64 + t] = f2b(o);
}

// ---------------- selection head ----------------
__global__ __launch_bounds__(64) void final_head(const u16* __restrict__ patb, const float* __restrict__ learned,
                                                 const float* __restrict__ content, const void* __restrict__ gum,
                                                 const void* __restrict__ gw, const void* __restrict__ gb,
                                                 const void* __restrict__ anw, const void* __restrict__ anb,
                                                 void* __restrict__ outp, long oSC, long oSLOT, long oSOFT, long oAL,
                                                 const int* __restrict__ flagp)
{
    const int f = *flagp;
    int row = blockIdx.x;
    int t = threadIdx.x;
    float pa = 0.f, ps = 0.f;
    for (int j = t; j < 1024; j += 64) {
        float p = b2f(patb[(long)row * 1024 + j]);
        pa += p * ldx(anw, j, f);
        ps += p * ldx(gw, j, f);
    }
#pragma unroll
    for (int off = 32; off > 0; off >>= 1) { pa += __shfl_xor(pa, off); ps += __shfl_xor(ps, off); }
    float alpha = sigmoid_(pa + ldx(anb, 0, f));
    float score = sigmoid_(ps + ldx(gb, 0, f));
    float logit = alpha * learned[row * 64 + t] + (1.f - alpha) * content[row * 64 + t];
    float u = ldx(gum, row * 64 + t, f);
    float inner = -logf(u + 1e-8f) + 1e-8f;
    inner = fmaxf(inner, 1e-20f);
    float gg = -logf(inner);
    float l1 = logit + gg, l2 = logit;
    float m1 = l1, m2 = l2;
#pragma unroll
    for (int off = 32; off > 0; off >>= 1) { m1 = fmaxf(m1, __shfl_xor(m1, off)); m2 = fmaxf(m2, __shfl_xor(m2, off)); }
    float e1 = __expf(l1 - m1), e2 = __expf(l2 - m2);
    float s1 = e1, s2 = e2;
#pragma unroll
    for (int off = 32; off > 0; off >>= 1) { s1 += __shfl_xor(s1, off); s2 += __shfl_xor(s2, off); }
    stx(outp, oSLOT + row * 64 + t, e1 / s1, f);
    stx(outp, oSOFT + row * 64 + t, e2 / s2, f);
    if (t == 0) { stx(outp, oSC + row, score, f); stx(outp, oAL + row, alpha, f); }
}

// ---------------- host-side GEMM wrapper ----------------
static void launch_gemm(hipStream_t st, int outf32, int act, int trans, int acc,
                        const void* A, const void* B, const void* bias, void* C,
                        int M, int N, int K, int lda, int ldb, int ldc, float scale, int batch,
                        long aBase, long aD, long aO, long aI,
                        long bBase, long bD, long bO, long bI,
                        long cD, long cO, long cI,
                        long biasBase, int aIsIn, int bIsIn, int biasIsIn, const int* flagp)
{
    dim3 g(N / 64, (M + 63) / 64, batch);
#define PASS A, B, bias, C, M, N, K, lda, ldb, ldc, scale, aBase, aD, aO, aI, bBase, bD, bO, bI, \
             cD, cO, cI, biasBase, aIsIn, bIsIn, biasIsIn, flagp
    if (outf32)      gemm_nt<1, 0, 0, 0><<<g, 256, 0, st>>>(PASS);
    else if (act)    gemm_nt<0, 1, 0, 0><<<g, 256, 0, st>>>(PASS);
    else if (trans)  gemm_nt<0, 0, 1, 0><<<g, 256, 0, st>>>(PASS);
    else if (acc)    gemm_nt<0, 0, 0, 1><<<g, 256, 0, st>>>(PASS);
    else             gemm_nt<0, 0, 0, 0><<<g, 256, 0, st>>>(PASS);
#undef PASS
}

// ---------------- shared early-phase workspace offsets (both paths) ----------------
#define WS_CID     0L
#define WS_QB      2621440L
#define WS_KKB     6815744L
#define WS_VVT     8912896L
#define WS_SC      11010048L
#define WS_CTXCAT  0L
#define WS_CONTEXT 16777216L
#define WS_XF      0L

// conservative path (peak ~38 MiB)
#define CS_QKVB    33554432L
#define CS_PROJ    16777216L
#define CS_FFN1C   16777216L
#define CS_FFN2C   33554432L
#define CS_KVPATB  16777216L
#define CS_QPAT    20971520L
#define CS_PATSC   21004288L
#define CS_OPAT    21528576L
#define CS_PATF32  21790720L
#define CS_PATB    22315008L
#define CS_LEARN   22577152L
#define CS_SQP     22609920L
#define CS_SKE     22675456L
#define CS_CONT    22708224L
#define CS_FLAG    39845888L
#define CS_NEED    39845892L

// fast path (peak ~97.2 MiB); audited write-after-last-read on single stream
#define FP_QKV     33554432L    // S13-15 (50.33 MB)
#define FP_PROJ    16777216L    // S15-16 over CONTEXT(dead S12)
#define FP_FFN1    33554432L    // S17-18 (67.11 MB) over QKV(dead S15)
#define FP_FFN2    16777216L    // S18-19 over PROJ(dead S16)
#define FP_KVPAT   33554432L    // S21-24 (33.55 MB) over FFN1(dead S18)
#define FP_PATSC   16777216L    // S22-24 (4.19 MB) over FFN2(dead S19)
#define FP_QPAT    100663296L   // S20-22 (32 KB)
#define FP_OPAT    100696064L   // S24-25 (0.26 MB)
#define FP_PATF32  100958208L   // S25-26 f32 (0.52 MB)
#define FP_PATB    101482496L   // S26-31 (0.26 MB)
#define FP_LEARN   101744640L   // f32 (32 KB)
#define FP_SQP     101777408L   // (64 KB)
#define FP_SKE     101842944L   // (32 KB)
#define FP_CONT    101875712L   // f32 (32 KB)
#define FP_FLAG    101908480L
#define FP_NEED    101908484L

// output offsets (elements)
#define OUT_Y      0L
#define OUT_PAT    8388608L
#define OUT_SCORES 8519680L
#define OUT_SLOT   8519808L
#define OUT_SOFT   8528000L
#define OUT_ALPHA  8536192L

extern "C" void kernel_launch(void* const* d_in, const int* in_sizes, int n_in,
                              void* d_out, int out_size, void* d_ws, size_t ws_size,
                              hipStream_t stream)
{
    const void* x     = d_in[0];
    const void* cache = d_in[1];
    const void* slote = d_in[2];
    const void* lids  = d_in[3];
    const void* gum   = d_in[4];
    const void* le    = d_in[5];
    const void* awqkv = d_in[6];
    const void* abqkv = d_in[7];
    const void* awo   = d_in[8];
    const void* abo   = d_in[9];
    const void* pwqkv = d_in[10];
    const void* pbqkv = d_in[11];
    const void* pwo   = d_in[12];
    const void* pbo   = d_in[13];
    const void* pq    = d_in[14];
    const void* fw1   = d_in[15];
    const void* fb1   = d_in[16];
    const void* fw2   = d_in[17];
    const void* fb2   = d_in[18];
    const void* n1g   = d_in[19];
    const void* n1b   = d_in[20];
    const void* n2g   = d_in[21];
    const void* n2b   = d_in[22];
    const void* gw    = d_in[23];
    const void* gb    = d_in[24];
    const void* selw  = d_in[25];
    const void* selb  = d_in[26];
    const void* sqw   = d_in[27];
    const void* sqb   = d_in[28];
    const void* skw   = d_in[29];
    const void* skb   = d_in[30];
    const void* anw   = d_in[31];
    const void* anb   = d_in[32];
    const void* decw  = d_in[33];
    const void* decb  = d_in[34];
    const void* cqw   = d_in[35];
    const void* cqb   = d_in[36];
    const void* ckw   = d_in[37];
    const void* ckb   = d_in[38];
    const void* cvw   = d_in[39];
    const void* cvb   = d_in[40];
    const void* fgw   = d_in[41];
    const void* fgb   = d_in[42];

    char* ws = (char*)d_ws;
    auto W  = [&](long off) { return (u16*)(ws + off); };
    auto Wf = [&](long off) { return (float*)(ws + off); };

    const bool fast = ws_size >= (size_t)FP_NEED;
    int* flg = (int*)(ws + (fast ? FP_FLAG : CS_FLAG));
    const long oQPAT   = fast ? FP_QPAT   : CS_QPAT;
    const long oOPAT   = fast ? FP_OPAT   : CS_OPAT;
    const long oPATF32 = fast ? FP_PATF32 : CS_PATF32;
    const long oPATB   = fast ? FP_PATB   : CS_PATB;
    const long oLEARN  = fast ? FP_LEARN  : CS_LEARN;
    const long oSQP    = fast ? FP_SQP    : CS_SQP;
    const long oSKE    = fast ? FP_SKE    : CS_SKE;
    const long oCONT   = fast ? FP_CONT   : CS_CONT;

    // S0) dtype detect
    detect_dtype<<<1, 1, 0, stream>>>((const u16*)n1g, flg);
    // S1) cid = concat(cache, layer_ids)
    build_cid<<<dim3((4096 * 320 + 255) / 256), 256, 0, stream>>>(cache, lids, W(WS_CID), flg);
    // S2) q = x @ cq_w^T + cq_b
    launch_gemm(stream, 0, 0, 0, 0, x, cqw, cqb, W(WS_QB), 8192, 256, 1024, 1024, 1024, 256, 1.f, 1,
                0, 1, 0, 0, 0, 1, 0, 0, 1, 0, 0, 0, 1, 1, 1, flg);
    // S3) kk = cid @ ck_w^T + ck_b
    launch_gemm(stream, 0, 0, 0, 0, W(WS_CID), ckw, ckb, W(WS_KKB), 4096, 256, 320, 320, 320, 256, 1.f, 1,
                0, 1, 0, 0, 0, 1, 0, 0, 1, 0, 0, 0, 0, 1, 1, flg);
    // S4) vvT[b] = (cid[b] @ cv_w^T + cv_b)^T
    launch_gemm(stream, 0, 0, 1, 0, W(WS_CID), cvw, cvb, W(WS_VVT), 512, 256, 320, 320, 320, 512, 1.f, 8,
                0, 1, 163840, 0, 0, 1, 0, 0, 1, 131072, 0, 0, 0, 1, 1, flg);
    // S5) sc[b] = q[b] @ kk[b]^T / 16
    launch_gemm(stream, 0, 0, 0, 0, W(WS_QB), W(WS_KKB), nullptr, W(WS_SC), 1024, 512, 256, 256, 256, 512,
                0.0625f, 8, 0, 1, 262144, 0, 0, 1, 131072, 0, 1, 524288, 0, 0, 0, 0, 0, flg);
    // S6) softmax over 512, in place
    softmax_inplace<<<8192, 256, 0, stream>>>(W(WS_SC), 512);
    // S7) ctx[b] = attn[b] @ vvT[b]^T -> ctxcat cols 0..255
    launch_gemm(stream, 0, 0, 0, 0, W(WS_SC), W(WS_VVT), nullptr, W(WS_CTXCAT), 1024, 256, 512, 512, 512, 320,
                1.f, 8, 0, 1, 524288, 0, 0, 1, 131072, 0, 1, 327680, 0, 0, 0, 0, 0, flg);
    // S8) ctxcat cols 256..319 = layer_embed
    fill_ctx_le<<<dim3((8192 * 64 + 255) / 256), 256, 0, stream>>>(le, W(WS_CTXCAT), flg);
    // S10) context = ctxcat @ dec_w^T + dec_b
    launch_gemm(stream, 0, 0, 0, 0, W(WS_CTXCAT), decw, decb, W(WS_CONTEXT), 8192, 1024, 320, 320, 320, 1024,
                1.f, 1, 0, 1, 0, 0, 0, 1, 0, 0, 1, 0, 0, 0, 0, 1, 1, flg);
    // S11a) gate logits = x @ fg_w[:, :1024]^T + fg_b
    launch_gemm(stream, 0, 0, 0, 0, x, fgw, fgb, W(WS_XF), 8192, 1024, 1024, 1024, 2048, 1024, 1.f, 1,
                0, 1, 0, 0, 0, 1, 0, 0, 1, 0, 0, 0, 1, 1, 1, flg);
    // S11b) gate logits += context @ fg_w[:, 1024:]^T
    launch_gemm(stream, 0, 0, 0, 1, W(WS_CONTEXT), fgw, nullptr, W(WS_XF), 8192, 1024, 1024, 1024, 2048, 1024,
                1.f, 1, 0, 1, 0, 0, 1024, 1, 0, 0, 1, 0, 0, 0, 0, 1, 0, flg);
    // S12) xf = sigmoid(gate)*x + (1-sigmoid)*context  (in place)
    fusion<<<32768, 256, 0, stream>>>(x, W(WS_CONTEXT), W(WS_XF), flg);

    if (fast) {
        // S13) full QKV = xf @ attn_wqkv^T + b  [8192, 3072]
        launch_gemm(stream, 0, 0, 0, 0, W(WS_XF), awqkv, abqkv, W(FP_QKV), 8192, 3072, 1024,
                    1024, 1024, 3072, 1.f, 1, 0, 1, 0, 0, 0, 1, 0, 0, 1, 0, 0, 0, 0, 1, 1, flg);
        // S14) flash attention, all batches, in-place O over q slices
        attn_self<<<dim3(4, 16, 8), 256, 0, stream>>>(W(FP_QKV), W(FP_QKV), 3072, 3145728L);
        // S15) proj = O @ attn_wo^T + b   (A rows stride 3072)
        launch_gemm(stream, 0, 0, 0, 0, W(FP_QKV), awo, abo, W(FP_PROJ), 8192, 1024, 1024,
                    3072, 1024, 1024, 1.f, 1, 0, 1, 0, 0, 0, 1, 0, 0, 1, 0, 0, 0, 0, 1, 1, flg);
        // S16) xf2 = LN(xf + proj), in place
        add_ln<<<8192, 256, 0, stream>>>(W(WS_XF), W(FP_PROJ), n1g, n1b, W(WS_XF), nullptr, 0, flg);
        // S17) ffn1 = gelu(xf2 @ w1^T + b1)  [8192, 4096]
        launch_gemm(stream, 0, 1, 0, 0, W(WS_XF), fw1, fb1, W(FP_FFN1), 8192, 4096, 1024,
                    1024, 1024, 4096, 1.f, 1, 0, 1, 0, 0, 0, 1, 0, 0, 1, 0, 0, 0, 0, 1, 1, flg);
        // S18) ffn2 = ffn1 @ w2^T + b2
        launch_gemm(stream, 0, 0, 0, 0, W(FP_FFN1), fw2, fb2, W(FP_FFN2), 8192, 1024, 4096,
                    4096, 4096, 1024, 1.f, 1, 0, 1, 0, 0, 0, 1, 0, 0, 1, 0, 0, 0, 0, 1, 1, flg);
        // S19) y = LN(xf2 + ffn2), in place + to out
        add_ln<<<8192, 256, 0, stream>>>(W(WS_XF), W(FP_FFN2), n2g, n2b, W(WS_XF), d_out, OUT_Y, flg);
        // S20) qpat
        launch_gemm(stream, 0, 0, 0, 0, pq, pwqkv, pbqkv, W(oQPAT), 16, 1024, 1024, 1024, 1024, 1024, 1.f, 1,
                    0, 1, 0, 0, 0, 1, 0, 0, 1, 0, 0, 0, 1, 1, 1, flg);
        // S21) kvpat full = y @ wkv^T + bkv  [8192, 2048]
        launch_gemm(stream, 0, 0, 0, 0, W(WS_XF), pwqkv, pbqkv, W(FP_KVPAT), 8192, 2048, 1024,
                    1024, 1024, 2048, 1.f, 1, 0, 1, 0, 0, 1048576, 1, 0, 0, 1, 0, 0, 1024, 0, 1, 1, flg);
        // S22) pattern scores, batch=128 over (b,h)
        launch_gemm(stream, 0, 0, 0, 0, W(oQPAT), W(FP_KVPAT), nullptr, W(FP_PATSC), 16, 1024, 64,
                    1024, 2048, 1024, 0.125f, 128,
                    0, 16, 0, 64, 0, 16, 2097152, 64, 1, 16384, 0, 0, 0, 0, 0, flg);
        // S23) softmax over 1024, 2048 rows in place
        softmax_inplace<<<2048, 256, 0, stream>>>(W(FP_PATSC), 1024);
        // S24) PV all batches
        pat_pv<<<dim3(16, 16, 8), 64, 0, stream>>>(W(FP_PATSC), W(FP_KVPAT), W(oOPAT),
                                                   262144L, 2097152L, 16384L);
    } else {
        // S13-15) per-batch attention pipeline
        for (int b = 0; b < 8; ++b) {
            launch_gemm(stream, 0, 0, 0, 0, W(WS_XF) + (long)b * 1048576, awqkv, abqkv, W(CS_QKVB),
                        1024, 3072, 1024, 1024, 1024, 3072, 1.f, 1,
                        0, 1, 0, 0, 0, 1, 0, 0, 1, 0, 0, 0, 0, 1, 1, flg);
            attn_self<<<dim3(4, 16, 1), 256, 0, stream>>>(W(CS_QKVB), W(CS_QKVB), 3072, 0L);
            launch_gemm(stream, 0, 0, 0, 0, W(CS_QKVB), awo, abo, W(CS_PROJ) + (long)b * 1048576,
                        1024, 1024, 1024, 3072, 1024, 1024, 1.f, 1,
                        0, 1, 0, 0, 0, 1, 0, 0, 1, 0, 0, 0, 0, 1, 1, flg);
        }
        add_ln<<<8192, 256, 0, stream>>>(W(WS_XF), W(CS_PROJ), n1g, n1b, W(WS_XF), nullptr, 0, flg);
        for (int c = 0; c < 4; ++c) {
            u16* xf2c = W(WS_XF) + (long)c * 2048 * 1024;
            launch_gemm(stream, 0, 1, 0, 0, xf2c, fw1, fb1, W(CS_FFN1C), 2048, 4096, 1024, 1024, 1024, 4096,
                        1.f, 1, 0, 1, 0, 0, 0, 1, 0, 0, 1, 0, 0, 0, 0, 1, 1, flg);
            launch_gemm(stream, 0, 0, 0, 0, W(CS_FFN1C), fw2, fb2, W(CS_FFN2C), 2048, 1024, 4096,
                        4096, 4096, 1024, 1.f, 1, 0, 1, 0, 0, 0, 1, 0, 0, 1, 0, 0, 0, 0, 1, 1, flg);
            add_ln<<<2048, 256, 0, stream>>>(xf2c, W(CS_FFN2C), n2g, n2b, xf2c, d_out,
                                             OUT_Y + (long)c * 2048 * 1024, flg);
        }
        launch_gemm(stream, 0, 0, 0, 0, pq, pwqkv, pbqkv, W(oQPAT), 16, 1024, 1024, 1024, 1024, 1024, 1.f, 1,
                    0, 1, 0, 0, 0, 1, 0, 0, 1, 0, 0, 0, 1, 1, 1, flg);
        for (int b = 0; b < 8; ++b) {
            const u16* yb = W(WS_XF) + (long)b * 1048576;
            launch_gemm(stream, 0, 0, 0, 0, yb, pwqkv, pbqkv, W(CS_KVPATB), 1024, 2048, 1024,
                        1024, 1024, 2048, 1.f, 1, 0, 1, 0, 0, 1048576, 1, 0, 0, 1, 0, 0, 1024, 0, 1, 1, flg);
            launch_gemm(stream, 0, 0, 0, 0, W(oQPAT), W(CS_KVPATB), nullptr, W(CS_PATSC), 16, 1024, 64,
                        1024, 2048, 1024, 0.125f, 16,
                        0, 16, 0, 64, 0, 16, 0, 64, 1, 16384, 0, 0, 0, 0, 0, flg);
            softmax_inplace<<<256, 256, 0, stream>>>(W(CS_PATSC), 1024);
            pat_pv<<<dim3(16, 16, 1), 64, 0, stream>>>(W(CS_PATSC), W(CS_KVPATB),
                                                       W(oOPAT) + (long)b * 16384, 0L, 0L, 0L);
        }
    }

    // S25) patterns = opat @ pat_wo^T + pat_bo (f32)
    launch_gemm(stream, 1, 0, 0, 0, W(oOPAT), pwo, pbo, Wf(oPATF32), 128, 1024, 1024, 1024, 1024, 1024,
                1.f, 1, 0, 1, 0, 0, 0, 1, 0, 0, 1, 0, 0, 0, 0, 1, 1, flg);
    // S26) cast patterns -> ws bf16 + d_out
    cast_pat<<<512, 256, 0, stream>>>(Wf(oPATF32), W(oPATB), d_out, OUT_PAT, flg);
    // S27) learned (f32)
    launch_gemm(stream, 1, 0, 0, 0, W(oPATB), selw, selb, Wf(oLEARN), 128, 64, 1024, 1024, 1024, 64,
                1.f, 1, 0, 1, 0, 0, 0, 1, 0, 0, 1, 0, 0, 0, 0, 1, 1, flg);
    // S28) sqp
    launch_gemm(stream, 0, 0, 0, 0, W(oPATB), sqw, sqb, W(oSQP), 128, 256, 1024, 1024, 1024, 256, 1.f, 1,
                0, 1, 0, 0, 0, 1, 0, 0, 1, 0, 0, 0, 0, 1, 1, flg);
    // S29) ske
    launch_gemm(stream, 0, 0, 0, 0, slote, skw, skb, W(oSKE), 64, 256, 256, 256, 256, 256, 1.f, 1,
                0, 1, 0, 0, 0, 1, 0, 0, 1, 0, 0, 0, 1, 1, 1, flg);
    // S30) content (f32)
    launch_gemm(stream, 1, 0, 0, 0, W(oSQP), W(oSKE), nullptr, Wf(oCONT), 128, 64, 256, 256, 256, 64,
                0.0625f, 1, 0, 1, 0, 0, 0, 1, 0, 0, 1, 0, 0, 0, 0, 0, 0, flg);
    // S31) selection head outputs
    final_head<<<128, 64, 0, stream>>>(W(oPATB), Wf(oLEARN), Wf(oCONT), gum, gw, gb, anw, anb,
                                       d_out, OUT_SCORES, OUT_SLOT, OUT_SOFT, OUT_ALPHA, flg);
}